// Round 4
// baseline (577.855 us; speedup 1.0000x reference)
//
#include <hip/hip_runtime.h>

// TopKActivation: per row of [4096, 16384] fp32, keep top-k (k=128) values in
// place, zero the rest. One block per row; 1024 threads, 16 elems/thread so
// keys stay in REGISTERS (R2 post-mortem: 64/thread spilled to scratch,
// VGPR_Count=60 proved it). Exact threshold via bitwise binary search with
// ballot-counting + compacted-LDS refinement. Non-temporal output stores keep
// the input L3-resident. (R3: nontemporal builtin needs a clang ext_vector
// type, not HIP's float4 class — v4f below.)

constexpr int COLS  = 16384;
constexpr int NT    = 1024;            // threads per block
constexpr int PER_T = COLS / NT;       // 16 elements per thread
constexpr int NV4   = PER_T / 4;       // 4 float4 per thread
constexpr int NW    = NT / 64;         // 16 waves
constexpr int CAP   = 2048;            // compacted-candidate capacity

typedef float v4f __attribute__((ext_vector_type(4)));

// Monotone float->uint key: order(key) == order(float), all finite values.
__device__ __forceinline__ unsigned int f2key(float f) {
  unsigned int b = __float_as_uint(f);
  return b ^ ((unsigned int)((int)b >> 31) | 0x80000000u);
}
__device__ __forceinline__ float key2f(unsigned int k) {
  unsigned int b = (k & 0x80000000u) ? (k ^ 0x80000000u) : ~k;
  return __uint_as_float(b);
}

__global__ void __launch_bounds__(NT)
topk_scatter_kernel(const float* __restrict__ x, const int* __restrict__ kptr,
                    float* __restrict__ out) {
  const int t    = threadIdx.x;
  const int lane = t & 63;
  const int wid  = t >> 6;
  const long long row = blockIdx.x;
  const int K = *kptr;   // 128

  __shared__ int red[2][NW];                // per-wave counts, parity-buffered
  __shared__ unsigned int cand[CAP];        // compacted candidate keys
  __shared__ int cand_n;
  __shared__ unsigned int flags[COLS / 32]; // rare-path tie bitmask (2 KB)

  const float4* xrow = reinterpret_cast<const float4*>(x + row * COLS);
  v4f*          orow = reinterpret_cast<v4f*>(out + row * COLS);

  // ---- load + transform; keys stay in registers (16/thread) -------------
  unsigned int key[PER_T];
  #pragma unroll
  for (int r = 0; r < NV4; ++r) {
    float4 v = xrow[r * NT + t];
    key[4 * r + 0] = f2key(v.x);
    key[4 * r + 1] = f2key(v.y);
    key[4 * r + 2] = f2key(v.z);
    key[4 * r + 3] = f2key(v.w);
  }

  // ---- exact k-th largest key via binary search on key bits -------------
  // Invariants: count_ge(lo) >= K (cnt_lo), count_ge(hi+1) < K (cnt_hi1).
  unsigned int lo = 0u, hi = 0xFFFFFFFFu;
  int cnt_lo = COLS, cnt_hi1 = 0;
  int base = 0, cN = 0;
  bool compacted = false;
  int par = 0;

  while (lo < hi) {
    const unsigned int mid = lo + ((hi - lo) >> 1) + 1u;  // in [lo+1, hi]
    int c;
    if (!compacted) {
      // full-data count: 1 v_cmp + popc per 64 elements, wave-uniform result
      int cw = 0;
      #pragma unroll
      for (int r = 0; r < PER_T; ++r)
        cw += __popcll(__ballot(key[r] >= mid));
      if (lane == 0) red[par][wid] = cw;
      __syncthreads();
      c = 0;
      #pragma unroll
      for (int w = 0; w < NW; ++w) c += red[par][w];
      par ^= 1;
    } else {
      // each wave redundantly counts the whole compacted list: no barriers
      int cw = 0;
      for (int j0 = 0; j0 < cN; j0 += 64) {
        const int j = j0 + lane;
        const unsigned int v = (j < cN) ? cand[j] : 0u;  // mid >= 1, so 0 fails
        cw += __popcll(__ballot(v >= mid));
      }
      c = base + cw;
    }

    if (c >= K) { lo = mid; cnt_lo = c; }
    else        { hi = mid - 1u; cnt_hi1 = c; }

    if (!compacted && lo < hi && (cnt_lo - cnt_hi1) <= CAP) {
      // compact all keys in [lo, hi] into LDS; exactly cnt_lo - cnt_hi1 of them
      if (t == 0) cand_n = 0;
      __syncthreads();
      #pragma unroll
      for (int r = 0; r < PER_T; ++r) {
        const unsigned int kk = key[r];
        if (kk >= lo && kk <= hi) {
          const int p = atomicAdd(&cand_n, 1);
          cand[p] = kk;
        }
      }
      __syncthreads();
      cN = cnt_lo - cnt_hi1;
      base = cnt_hi1;
      compacted = true;
    }
  }

  const unsigned int T = lo;           // k-th largest key
  const int E = cnt_lo - cnt_hi1;      // # elements equal to T
  const int R = K - cnt_hi1;           // how many equals to keep (>=1)
  const bool need_rank = (E != R);     // duplicates straddling the boundary

  if (need_rank) {
    // rare path: mark all equal elements, keep the R lowest-indexed ones
    for (int w = t; w < COLS / 32; w += NT) flags[w] = 0u;
    __syncthreads();
    #pragma unroll
    for (int r = 0; r < NV4; ++r) {
      #pragma unroll
      for (int j = 0; j < 4; ++j) {
        if (key[4 * r + j] == T) {
          const int col = (r * NT + t) * 4 + j;
          atomicOr(&flags[col >> 5], 1u << (col & 31));
        }
      }
    }
    __syncthreads();
  }

  // ---- write pass: val if kept, else 0; non-temporal stores -------------
  #pragma unroll
  for (int r = 0; r < NV4; ++r) {
    v4f vals;
    #pragma unroll
    for (int j = 0; j < 4; ++j) {
      const unsigned int kk = key[4 * r + j];
      bool keep;
      if (kk > T) {
        keep = true;
      } else if (kk == T) {
        if (!need_rank) {
          keep = true;
        } else {
          const int col = (r * NT + t) * 4 + j;
          const int w_hi = col >> 5;
          int rank = 0;
          for (int w = 0; w < w_hi; ++w) rank += __popc(flags[w]);
          rank += __popc(flags[w_hi] & ((1u << (col & 31)) - 1u));
          keep = (rank < R);
        }
      } else {
        keep = false;
      }
      vals[j] = keep ? key2f(kk) : 0.0f;
    }
    __builtin_nontemporal_store(vals, &orow[r * NT + t]);
  }
}

extern "C" void kernel_launch(void* const* d_in, const int* in_sizes, int n_in,
                              void* d_out, int out_size, void* d_ws, size_t ws_size,
                              hipStream_t stream) {
  const float* x    = (const float*)d_in[0];
  const int*   kptr = (const int*)d_in[1];
  float*       out  = (float*)d_out;
  const int rows = in_sizes[0] / COLS;  // 4096
  topk_scatter_kernel<<<rows, NT, 0, stream>>>(x, kptr, out);
}

// Round 5
// 448.301 us; speedup vs baseline: 1.2890x; 1.2890x over previous
//
#include <hip/hip_runtime.h>

// TopKActivation: per row of [4096, 16384] fp32, keep top-k (k=128), zero the
// rest. R4 post-mortem: barrier-per-iteration + 16 waves redundantly scanning
// the 2048-entry LDS candidate list saturated the LDS port (295 us, VALU 48%,
// HBM 1.4 TB/s). New structure: ONE ballot pass brackets the threshold with a
// statistical window [1.9, 3.2) (count ~460 +/- 21 for N(0,1) rows; cap 1024 is
// +26 sigma), compact once to LDS, then WAVE 0 finishes the bisection on
// register-resident candidates -- 3 barriers/block total, no LDS re-scans.
// Exact fallback loop (R2/R4-proven) preserves correctness for any input.

constexpr int COLS  = 16384;
constexpr int NT    = 1024;            // threads per block
constexpr int PER_T = COLS / NT;       // 16 elements per thread
constexpr int NV4   = PER_T / 4;       // 4 float4 per thread
constexpr int NW    = NT / 64;         // 16 waves
constexpr int CAP   = 2048;            // LDS candidate buffer
constexpr int CAPW  = 1024;            // fast-path window cap (16 regs in wave0)
constexpr int NREG  = CAPW / 64;       // 16

typedef float v4f __attribute__((ext_vector_type(4)));

// Monotone float->uint key: order(key) == order(float), all finite values.
__device__ __forceinline__ unsigned int f2key(float f) {
  unsigned int b = __float_as_uint(f);
  return b ^ ((unsigned int)((int)b >> 31) | 0x80000000u);
}
__device__ __forceinline__ float key2f(unsigned int k) {
  unsigned int b = (k & 0x80000000u) ? (k ^ 0x80000000u) : ~k;
  return __uint_as_float(b);
}

__global__ void __launch_bounds__(NT)
topk_scatter_kernel(const float* __restrict__ x, const int* __restrict__ kptr,
                    float* __restrict__ out) {
  const int t    = threadIdx.x;
  const int lane = t & 63;
  const int wid  = t >> 6;
  const long long row = blockIdx.x;
  const int K = *kptr;   // 128

  __shared__ int redA[NW], redB[NW];        // initial bracket counts
  __shared__ int red2[2][NW];               // fallback reduce, parity-buffered
  __shared__ unsigned int cand[CAP];        // compacted candidate keys
  __shared__ int cand_n;
  __shared__ unsigned int sT;               // broadcast: threshold key
  __shared__ int sE, sR;                    // broadcast: eq-count, keep-count
  __shared__ unsigned int flags[COLS / 32]; // rare-path tie bitmask (2 KB)

  const float4* xrow = reinterpret_cast<const float4*>(x + row * COLS);
  v4f*          orow = reinterpret_cast<v4f*>(out + row * COLS);

  // ---- load + transform; keys stay in registers (16/thread) -------------
  unsigned int key[PER_T];
  #pragma unroll
  for (int r = 0; r < NV4; ++r) {
    float4 v = xrow[r * NT + t];
    key[4 * r + 0] = f2key(v.x);
    key[4 * r + 1] = f2key(v.y);
    key[4 * r + 2] = f2key(v.z);
    key[4 * r + 3] = f2key(v.w);
  }

  // ---- bracket pass: count >= A and >= B in one register sweep ----------
  const unsigned int A = f2key(1.9f);
  const unsigned int B = f2key(3.2f);
  int cwA = 0, cwB = 0;
  #pragma unroll
  for (int r = 0; r < PER_T; ++r) {
    cwA += __popcll(__ballot(key[r] >= A));
    cwB += __popcll(__ballot(key[r] >= B));
  }
  if (lane == 0) { redA[wid] = cwA; redB[wid] = cwB; }
  if (t == 0) cand_n = 0;
  __syncthreads();                                   // barrier 1
  int cA = 0, cB = 0;
  #pragma unroll
  for (int w = 0; w < NW; ++w) { cA += redA[w]; cB += redB[w]; }

  unsigned int T;
  int E, R;
  const bool fast = (cA >= K) && (cB < K) && ((cA - cB) <= CAPW);

  if (fast) {
    // ---- compact window candidates to LDS (once) ------------------------
    #pragma unroll
    for (int r = 0; r < PER_T; ++r) {
      const unsigned int kk = key[r];
      if (kk >= A && kk < B) {
        const int p = atomicAdd(&cand_n, 1);
        cand[p] = kk;
      }
    }
    __syncthreads();                                 // barrier 2

    // ---- wave 0: register-resident bisection, no barriers ---------------
    if (wid == 0) {
      const int NC = cA - cB;                        // >=1 guaranteed
      unsigned int creg[NREG];
      #pragma unroll
      for (int j = 0; j < NREG; ++j) {
        const int idx = j * 64 + lane;
        creg[j] = (idx < NC) ? cand[idx] : 0u;       // pad key 0 < any mid
      }
      unsigned int lo = A, hi = B - 1u;
      int cnt_lo = cA, cnt_hi1 = cB;
      const int nreg_used = (NC + 63) >> 6;
      while (lo < hi) {
        const unsigned int mid = lo + ((hi - lo) >> 1) + 1u;
        int c = cB;
        #pragma unroll
        for (int j = 0; j < NREG; ++j)
          if (j < nreg_used) c += __popcll(__ballot(creg[j] >= mid));
        if (c >= K) { lo = mid; cnt_lo = c; }
        else        { hi = mid - 1u; cnt_hi1 = c; }
      }
      if (lane == 0) { sT = lo; sE = cnt_lo - cnt_hi1; sR = K - cnt_hi1; }
    }
    __syncthreads();                                 // barrier 3
    T = sT; E = sE; R = sR;
  } else {
    // ---- exact fallback: full bitwise bisection (R2/R4-proven) ----------
    unsigned int lo = 0u, hi = 0xFFFFFFFFu;
    int cnt_lo = COLS, cnt_hi1 = 0;
    int base = 0, cN = 0;
    bool compacted = false;
    int par = 0;
    while (lo < hi) {
      const unsigned int mid = lo + ((hi - lo) >> 1) + 1u;
      int c;
      if (!compacted) {
        int cw = 0;
        #pragma unroll
        for (int r = 0; r < PER_T; ++r)
          cw += __popcll(__ballot(key[r] >= mid));
        if (lane == 0) red2[par][wid] = cw;
        __syncthreads();
        c = 0;
        #pragma unroll
        for (int w = 0; w < NW; ++w) c += red2[par][w];
        par ^= 1;
      } else {
        int cw = 0;
        for (int j0 = 0; j0 < cN; j0 += 64) {
          const int j = j0 + lane;
          const unsigned int v = (j < cN) ? cand[j] : 0u;
          cw += __popcll(__ballot(v >= mid));
        }
        c = base + cw;
      }
      if (c >= K) { lo = mid; cnt_lo = c; }
      else        { hi = mid - 1u; cnt_hi1 = c; }

      if (!compacted && lo < hi && (cnt_lo - cnt_hi1) <= CAP) {
        if (t == 0) cand_n = 0;
        __syncthreads();
        #pragma unroll
        for (int r = 0; r < PER_T; ++r) {
          const unsigned int kk = key[r];
          if (kk >= lo && kk <= hi) {
            const int p = atomicAdd(&cand_n, 1);
            cand[p] = kk;
          }
        }
        __syncthreads();
        cN = cnt_lo - cnt_hi1;
        base = cnt_hi1;
        compacted = true;
      }
    }
    T = lo; E = cnt_lo - cnt_hi1; R = K - cnt_hi1;
  }

  const bool need_rank = (E != R);     // duplicates straddling the boundary

  if (need_rank) {
    // rare path: mark all equal elements, keep the R lowest-indexed ones
    for (int w = t; w < COLS / 32; w += NT) flags[w] = 0u;
    __syncthreads();
    #pragma unroll
    for (int r = 0; r < NV4; ++r) {
      #pragma unroll
      for (int j = 0; j < 4; ++j) {
        if (key[4 * r + j] == T) {
          const int col = (r * NT + t) * 4 + j;
          atomicOr(&flags[col >> 5], 1u << (col & 31));
        }
      }
    }
    __syncthreads();
  }

  // ---- write pass: val if kept, else 0; non-temporal stores -------------
  #pragma unroll
  for (int r = 0; r < NV4; ++r) {
    v4f vals;
    #pragma unroll
    for (int j = 0; j < 4; ++j) {
      const unsigned int kk = key[4 * r + j];
      bool keep;
      if (kk > T) {
        keep = true;
      } else if (kk == T) {
        if (!need_rank) {
          keep = true;
        } else {
          const int col = (r * NT + t) * 4 + j;
          const int w_hi = col >> 5;
          int rank = 0;
          for (int w = 0; w < w_hi; ++w) rank += __popc(flags[w]);
          rank += __popc(flags[w_hi] & ((1u << (col & 31)) - 1u));
          keep = (rank < R);
        }
      } else {
        keep = false;
      }
      vals[j] = keep ? key2f(kk) : 0.0f;
    }
    __builtin_nontemporal_store(vals, &orow[r * NT + t]);
  }
}

extern "C" void kernel_launch(void* const* d_in, const int* in_sizes, int n_in,
                              void* d_out, int out_size, void* d_ws, size_t ws_size,
                              hipStream_t stream) {
  const float* x    = (const float*)d_in[0];
  const int*   kptr = (const int*)d_in[1];
  float*       out  = (float*)d_out;
  const int rows = in_sizes[0] / COLS;  // 4096
  topk_scatter_kernel<<<rows, NT, 0, stream>>>(x, kptr, out);
}